// Round 4
// baseline (525.022 us; speedup 1.0000x reference)
//
#include <hip/hip_runtime.h>
#include <hip/hip_bf16.h>

#define HD 128
#define NEG_SLOPE 0.2f

typedef __attribute__((ext_vector_type(8))) short short8;
typedef __attribute__((ext_vector_type(4))) float f32x4;

__device__ __forceinline__ float lrelu(float x) {
    return x > 0.f ? x : NEG_SLOPE * x;
}
__device__ __forceinline__ ushort f2bf(float f) {
    __hip_bfloat16 h = __float2bfloat16(f);
    return *(ushort*)&h;
}
__device__ __forceinline__ float bflo(unsigned u) { return __uint_as_float(u << 16); }
__device__ __forceinline__ float bfhi(unsigned u) { return __uint_as_float(u & 0xffff0000u); }

// ---------- fused prep: v-vectors + Wt (bf16 transpose) + zero counts ----------
__global__ void k_prep(const float* __restrict__ Ws, const float* __restrict__ Wd,
                       const float* __restrict__ a_s, const float* __restrict__ a_d,
                       float* __restrict__ v, ushort* __restrict__ Wt,
                       int* __restrict__ counts, int nTot) {
    int t = blockIdx.x * blockDim.x + threadIdx.x;
    if (t < nTot) counts[t] = 0;
    if (t < 768) {
        int c = t >> 8;
        int sd = (t >> 7) & 1;
        int d = t & (HD - 1);
        const float* W = sd ? Wd : Ws;
        const float* a = sd ? a_d : a_s;
        const float* Wrow = W + ((size_t)c * HD + d) * HD;
        const float* av = a + c * HD;
        float s = 0.f;
        for (int h = 0; h < HD; h++) s += Wrow[h] * av[h];
        v[t] = s;
    }
    int u = t - 768;
    if (u >= 0 && u < 3 * HD * HD) {
        int c = u >> 14;
        int r = u & 16383;
        int n = r >> 7, k = r & 127;
        Wt[u] = f2bf(Ws[((size_t)c << 14) + k * HD + n]);
    }
}

// ---------- alpha[n] = x[n].v[slot] (<=4 slots) + optional bf16 copy of x ----------
template<bool CVT>
__global__ void k_alpha(const float* __restrict__ x, int N,
                        const float* __restrict__ v,
                        int i0, int i1, int i2, int i3,
                        float* __restrict__ o0, float* __restrict__ o1,
                        float* __restrict__ o2, float* __restrict__ o3, int nv,
                        unsigned* __restrict__ xb) {
    int lane = threadIdx.x & 63;
    int wid = (int)(((long long)blockIdx.x * blockDim.x + threadIdx.x) >> 6);
    int nwaves = (gridDim.x * blockDim.x) >> 6;
    float2 z = make_float2(0.f, 0.f);
    float2 vv0 = *(const float2*)&v[i0 * HD + lane * 2];
    float2 vv1 = (nv > 1) ? *(const float2*)&v[i1 * HD + lane * 2] : z;
    float2 vv2 = (nv > 2) ? *(const float2*)&v[i2 * HD + lane * 2] : z;
    float2 vv3 = (nv > 3) ? *(const float2*)&v[i3 * HD + lane * 2] : z;
    for (int n = wid; n < N; n += nwaves) {
        float2 xv = *(const float2*)&x[(long long)n * HD + lane * 2];
        if (CVT)
            xb[(size_t)n * 64 + lane] = (unsigned)f2bf(xv.x) | ((unsigned)f2bf(xv.y) << 16);
        float s0 = xv.x * vv0.x + xv.y * vv0.y;
        float s1 = xv.x * vv1.x + xv.y * vv1.y;
        float s2 = xv.x * vv2.x + xv.y * vv2.y;
        float s3 = xv.x * vv3.x + xv.y * vv3.y;
        #pragma unroll
        for (int off = 32; off; off >>= 1) {
            s0 += __shfl_xor(s0, off, 64);
            s1 += __shfl_xor(s1, off, 64);
            s2 += __shfl_xor(s2, off, 64);
            s3 += __shfl_xor(s3, off, 64);
        }
        if (lane == 0) {
            o0[n] = s0;
            if (nv > 1) o1[n] = s1;
            if (nv > 2) o2[n] = s2;
            if (nv > 3) o3[n] = s3;
        }
    }
}

// ---------- H16 = A * Wt^T (MFMA), A fp32 (cvt in-kernel) or pre-packed bf16 ----------
template<bool BF16IN>
__global__ __launch_bounds__(256) void k_gemm_mfma(const float* __restrict__ X,
                                                   const unsigned* __restrict__ XB,
                                                   const ushort* __restrict__ Wt,
                                                   ushort* __restrict__ H16, int nrows) {
    int tid = threadIdx.x;
    int lane = tid & 63;
    int wv = tid >> 6;
    int m = lane & 15;
    int kb = lane >> 4;
    long long row0 = (long long)blockIdx.x * 64 + wv * 16;
    long long ar = row0 + m;
    if (ar >= nrows) ar = nrows - 1;               // clamped read, store guarded
    const float* aptr = X ? (X + ar * HD + kb * 8) : nullptr;
    const ushort* abptr = BF16IN ? ((const ushort*)XB + ar * HD + kb * 8) : nullptr;
    const ushort* bptr = Wt + (size_t)m * HD + kb * 8;

    f32x4 acc[8];
    #pragma unroll
    for (int t = 0; t < 8; t++) acc[t] = (f32x4){0.f, 0.f, 0.f, 0.f};

    #pragma unroll
    for (int ks = 0; ks < 4; ks++) {
        short8 af;
        if (BF16IN) {
            af = *(const short8*)(abptr + ks * 32);
        } else {
            float4 a0 = *(const float4*)(aptr + ks * 32);
            float4 a1 = *(const float4*)(aptr + ks * 32 + 4);
            af[0] = (short)f2bf(a0.x); af[1] = (short)f2bf(a0.y);
            af[2] = (short)f2bf(a0.z); af[3] = (short)f2bf(a0.w);
            af[4] = (short)f2bf(a1.x); af[5] = (short)f2bf(a1.y);
            af[6] = (short)f2bf(a1.z); af[7] = (short)f2bf(a1.w);
        }
        #pragma unroll
        for (int t = 0; t < 8; t++) {
            short8 bf = *(const short8*)(bptr + (size_t)t * 16 * HD + ks * 32);
            acc[t] = __builtin_amdgcn_mfma_f32_16x16x32_bf16(af, bf, acc[t], 0, 0, 0);
        }
    }
    int rb = (lane >> 4) * 4;
    #pragma unroll
    for (int t = 0; t < 8; t++) {
        #pragma unroll
        for (int j = 0; j < 4; j++) {
            long long r = row0 + rb + j;
            if (r < nrows) H16[r * HD + t * 16 + m] = f2bf(acc[t][j]);
        }
    }
}

// ---------- CSR build (fused over 3 relations) ----------
__global__ void k_hist3(const int* __restrict__ d0, const int* __restrict__ d1,
                        const int* __restrict__ d2, int* __restrict__ counts,
                        int E, int off1, int off2) {
    int t = blockIdx.x * blockDim.x + threadIdx.x;
    if (t >= 3 * E) return;
    if (t < E)           atomicAdd(&counts[d0[t]], 1);
    else if (t < 2 * E)  atomicAdd(&counts[off1 + d1[t - E]], 1);
    else                 atomicAdd(&counts[off2 + d2[t - 2 * E]], 1);
}

__global__ void k_chunksum(const int* __restrict__ counts, int* __restrict__ chunkSum, int n) {
    __shared__ int sh[256];
    int i = blockIdx.x * 256 + threadIdx.x;
    sh[threadIdx.x] = (i < n) ? counts[i] : 0;
    __syncthreads();
    for (int off = 128; off; off >>= 1) {
        if (threadIdx.x < off) sh[threadIdx.x] += sh[threadIdx.x + off];
        __syncthreads();
    }
    if (threadIdx.x == 0) chunkSum[blockIdx.x] = sh[0];
}

__global__ void k_scanchunk(const int* __restrict__ chunkSum, int* __restrict__ chunkOff, int nChunk) {
    __shared__ int sh[1024];
    int t = threadIdx.x;
    int v = (t < nChunk) ? chunkSum[t] : 0;
    sh[t] = v;
    __syncthreads();
    for (int off = 1; off < 1024; off <<= 1) {
        int add = (t >= off) ? sh[t - off] : 0;
        __syncthreads();
        sh[t] += add;
        __syncthreads();
    }
    if (t < nChunk) chunkOff[t] = sh[t] - v; // exclusive
}

__global__ void k_rowstart(const int* __restrict__ counts, const int* __restrict__ chunkOff,
                           int* __restrict__ rowStart, int* __restrict__ fillPos, int n) {
    __shared__ int sh[256];
    int i = blockIdx.x * 256 + threadIdx.x;
    int t = threadIdx.x;
    int v = (i < n) ? counts[i] : 0;
    sh[t] = v;
    __syncthreads();
    for (int off = 1; off < 256; off <<= 1) {
        int add = (t >= off) ? sh[t - off] : 0;
        __syncthreads();
        sh[t] += add;
        __syncthreads();
    }
    if (i < n) {
        int rs = chunkOff[blockIdx.x] + sh[t] - v;
        rowStart[i] = rs;
        fillPos[i] = rs;
    }
}

__global__ void k_fill3(const int* __restrict__ s0, const int* __restrict__ d0,
                        const int* __restrict__ s1, const int* __restrict__ d1,
                        const int* __restrict__ s2, const int* __restrict__ d2,
                        int* __restrict__ fillPos, int* __restrict__ eSrc,
                        int E, int off1, int off2) {
    int t = blockIdx.x * blockDim.x + threadIdx.x;
    if (t >= 3 * E) return;
    int sv, p;
    if (t < E)          { sv = s0[t];         p = atomicAdd(&fillPos[d0[t]], 1); }
    else if (t < 2 * E) { int e = t - E;      sv = s1[e]; p = atomicAdd(&fillPos[off1 + d1[e]], 1); }
    else                { int e = t - 2 * E;  sv = s2[e]; p = atomicAdd(&fillPos[off2 + d2[e]], 1); }
    eSrc[p] = sv;
}

// ---------- fused per-dst softmax + 4-edge-parallel gather + bias/relu epilogue ----
// MODE 0: out = biasA+biasB + acc           (conv0, artwork block, first writer)
// MODE 1: out = relu(biasA + acc)           (conv1, artist block, only writer)
// MODE 2: out = relu(out + acc)             (conv2, artwork block, last writer)
template<int MODE>
__global__ __launch_bounds__(256) void k_agg(const int* __restrict__ eSrc,
                                             const int* __restrict__ rowStart,
                                             const int* __restrict__ counts,
                                             const float* __restrict__ as_,
                                             const float* __restrict__ ad_,
                                             const ushort* __restrict__ hs,
                                             const float* __restrict__ biasA,
                                             const float* __restrict__ biasB,
                                             float* __restrict__ out, int Nd) {
    int lane = threadIdx.x & 63;
    int d = (int)(((long long)blockIdx.x * blockDim.x + threadIdx.x) >> 6);
    if (d >= Nd) return;
    int sub = lane >> 4;        // edge slot 0..3
    int fl = lane & 15;         // feature block: features fl*8 .. fl*8+7
    int dg = counts[d];

    float acc[8];
    #pragma unroll
    for (int k = 0; k < 8; k++) acc[k] = 0.f;

    if (dg > 0) {
        int base = rowStart[d];
        float ad = ad_[d];
        if (dg <= 64) {
            int s = 0;
            float av = -1e30f;
            if (lane < dg) { s = eSrc[base + lane]; av = lrelu(as_[s] + ad); }
            float mm = av;
            #pragma unroll
            for (int off = 32; off; off >>= 1) mm = fmaxf(mm, __shfl_xor(mm, off, 64));
            float w = (lane < dg) ? __expf(av - mm) : 0.f;
            float den = w;
            #pragma unroll
            for (int off = 32; off; off >>= 1) den += __shfl_xor(den, off, 64);
            w *= (1.f / den);   // den >= 1 (max edge contributes exp(0))
            for (int j0 = 0; j0 < dg; j0 += 4) {
                int idx = j0 + sub;
                float wj = __shfl(w, idx, 64);   // 0 for idx >= dg
                int sj = __shfl(s, idx, 64);     // 0 for idx >= dg (safe row)
                uint4 u = *(const uint4*)((const unsigned*)hs + ((size_t)sj * HD + fl * 8) / 2);
                acc[0] += wj * bflo(u.x); acc[1] += wj * bfhi(u.x);
                acc[2] += wj * bflo(u.y); acc[3] += wj * bfhi(u.y);
                acc[4] += wj * bflo(u.z); acc[5] += wj * bfhi(u.z);
                acc[6] += wj * bflo(u.w); acc[7] += wj * bfhi(u.w);
            }
        } else {
            float mm = -1e30f;
            for (int i = lane; i < dg; i += 64)
                mm = fmaxf(mm, lrelu(as_[eSrc[base + i]] + ad));
            #pragma unroll
            for (int off = 32; off; off >>= 1) mm = fmaxf(mm, __shfl_xor(mm, off, 64));
            float den = 0.f;
            for (int i = lane; i < dg; i += 64)
                den += __expf(lrelu(as_[eSrc[base + i]] + ad) - mm);
            #pragma unroll
            for (int off = 32; off; off >>= 1) den += __shfl_xor(den, off, 64);
            float inv = 1.f / den;
            for (int c0 = 0; c0 < dg; c0 += 64) {
                int n = min(64, dg - c0);
                int s = 0; float w = 0.f;
                if (lane < n) {
                    s = eSrc[base + c0 + lane];
                    w = __expf(lrelu(as_[s] + ad) - mm) * inv;
                }
                for (int j0 = 0; j0 < n; j0 += 4) {
                    int idx = j0 + sub;
                    float wj = __shfl(w, idx, 64);
                    int sj = __shfl(s, idx, 64);
                    uint4 u = *(const uint4*)((const unsigned*)hs + ((size_t)sj * HD + fl * 8) / 2);
                    acc[0] += wj * bflo(u.x); acc[1] += wj * bfhi(u.x);
                    acc[2] += wj * bflo(u.y); acc[3] += wj * bfhi(u.y);
                    acc[4] += wj * bflo(u.z); acc[5] += wj * bfhi(u.z);
                    acc[6] += wj * bflo(u.w); acc[7] += wj * bfhi(u.w);
                }
            }
        }
        // fold the 4 edge slots: lanes with same fl sum up
        #pragma unroll
        for (int k = 0; k < 8; k++) {
            acc[k] += __shfl_xor(acc[k], 16, 64);
            acc[k] += __shfl_xor(acc[k], 32, 64);
        }
    }

    if (lane < 16) {
        float* orow = out + (size_t)d * HD + fl * 8;
        float vals[8];
        #pragma unroll
        for (int k = 0; k < 8; k++) {
            float bv;
            if (MODE == 0)      bv = biasA[fl * 8 + k] + biasB[fl * 8 + k];
            else if (MODE == 1) bv = biasA[fl * 8 + k];
            else                bv = orow[k];
            float o = bv + acc[k];
            vals[k] = (MODE >= 1) ? fmaxf(o, 0.f) : o;
        }
        *(float4*)&orow[0] = make_float4(vals[0], vals[1], vals[2], vals[3]);
        *(float4*)&orow[4] = make_float4(vals[4], vals[5], vals[6], vals[7]);
    }
}

extern "C" void kernel_launch(void* const* d_in, const int* in_sizes, int n_in,
                              void* d_out, int out_size, void* d_ws, size_t ws_size,
                              hipStream_t stream) {
    const float* x_artist  = (const float*)d_in[0];
    const float* x_artwork = (const float*)d_in[1];
    const int* srcA[3] = {(const int*)d_in[2], (const int*)d_in[4], (const int*)d_in[6]};
    const int* dstA[3] = {(const int*)d_in[3], (const int*)d_in[5], (const int*)d_in[7]};
    const float* Ws  = (const float*)d_in[8];
    const float* Wd  = (const float*)d_in[9];
    const float* a_s = (const float*)d_in[10];
    const float* a_d = (const float*)d_in[11];
    const float* b   = (const float*)d_in[12];
    float* out = (float*)d_out;

    const int Na = in_sizes[0] / HD;
    const int Nw = in_sizes[1] / HD;
    const int E  = in_sizes[2];
    const int nTot = Nw + Na + Nw;              // concatenated dst-node space
    const int nChunk = (nTot + 255) / 256;      // <= 1024 required

    // ---- workspace carve-up (4-byte words; all chunks 16B-aligned) ----
    float* ws = (float*)d_ws;
    size_t off = 0;
    float* v   = ws + off;  off += 768;
    float* as0 = ws + off;  off += Na;
    float* ad0 = ws + off;  off += Nw;
    float* as1 = ws + off;  off += Nw;
    float* ad1 = ws + off;  off += Na;
    float* as2 = ws + off;  off += Nw;
    float* ad2 = ws + off;  off += Nw;
    int* counts   = (int*)(ws + off); off += nTot;
    int* chunkSum = (int*)(ws + off); off += 1024;
    int* chunkOff = (int*)(ws + off); off += 1024;
    int* rowStart = (int*)(ws + off); off += nTot;
    int* fillPos  = (int*)(ws + off); off += nTot;
    int* eSrc     = (int*)(ws + off); off += (size_t)3 * E;
    ushort* Wt    = (ushort*)(ws + off); off += (3 * HD * HD) / 2;
    unsigned* xbW = (unsigned*)(ws + off); off += (size_t)Nw * (HD / 2);   // bf16 x_artwork
    ushort* hs16  = (ushort*)(ws + off); off += (size_t)Nw * HD / 2;
    if (ws_size < off * sizeof(float) || nChunk > 1024) return;

    // per-conv metadata
    const float* asP[3]   = {as0, as1, as2};
    const float* adP[3]   = {ad0, ad1, ad2};
    const int statOff[3]  = {0, Nw, Nw + Na};
    const int nsrc[3]     = {Na, Nw, Nw};
    const int ndst[3]     = {Nw, Na, Nw};
    const long long outBase[3] = {(long long)Na * HD, 0, (long long)Na * HD};

    const int B = 256;
    int prepN = nTot > (768 + 3 * HD * HD) ? nTot : (768 + 3 * HD * HD);

    k_prep<<<(prepN + B - 1) / B, B, 0, stream>>>(Ws, Wd, a_s, a_d, v, Wt, counts, nTot);

    // alphas: artist pass (slots vs0=0, vd1=3), artwork pass (vd0=1, vs1=2, vs2=4, vd2=5) + bf16 cvt
    k_alpha<false><<<1024, B, 0, stream>>>(x_artist, Na, v, 0, 3, 0, 0,
                                           as0, ad1, nullptr, nullptr, 2, nullptr);
    k_alpha<true><<<1024, B, 0, stream>>>(x_artwork, Nw, v, 1, 2, 4, 5,
                                          ad0, as1, as2, ad2, 4, xbW);

    // CSR build over concatenated dst space
    k_hist3<<<(3 * E + B - 1) / B, B, 0, stream>>>(dstA[0], dstA[1], dstA[2], counts,
                                                   E, statOff[1], statOff[2]);
    k_chunksum<<<nChunk, B, 0, stream>>>(counts, chunkSum, nTot);
    k_scanchunk<<<1, 1024, 0, stream>>>(chunkSum, chunkOff, nChunk);
    k_rowstart<<<nChunk, B, 0, stream>>>(counts, chunkOff, rowStart, fillPos, nTot);
    k_fill3<<<(3 * E + B - 1) / B, B, 0, stream>>>(srcA[0], dstA[0], srcA[1], dstA[1],
                                                   srcA[2], dstA[2], fillPos, eSrc,
                                                   E, statOff[1], statOff[2]);

    // per conv: hs GEMM (bf16 out, shared scratch) then gather-aggregate into d_out
    for (int c = 0; c < 3; c++) {
        if (c == 0)
            k_gemm_mfma<false><<<(nsrc[c] + 63) / 64, B, 0, stream>>>(
                x_artist, nullptr, Wt + (size_t)c * HD * HD, hs16, nsrc[c]);
        else
            k_gemm_mfma<true><<<(nsrc[c] + 63) / 64, B, 0, stream>>>(
                nullptr, xbW, Wt + (size_t)c * HD * HD, hs16, nsrc[c]);
        int nblk = (ndst[c] + 3) / 4; // 4 waves per 256-thread block, wave per dst
        if (c == 0)
            k_agg<0><<<nblk, B, 0, stream>>>(eSrc, rowStart + statOff[c], counts + statOff[c],
                                             asP[c], adP[c], hs16, b, b + 2 * HD,
                                             out + outBase[c], ndst[c]);
        else if (c == 1)
            k_agg<1><<<nblk, B, 0, stream>>>(eSrc, rowStart + statOff[c], counts + statOff[c],
                                             asP[c], adP[c], hs16, b + HD, nullptr,
                                             out + outBase[c], ndst[c]);
        else
            k_agg<2><<<nblk, B, 0, stream>>>(eSrc, rowStart + statOff[c], counts + statOff[c],
                                             asP[c], adP[c], hs16, nullptr, nullptr,
                                             out + outBase[c], ndst[c]);
    }
}

// Round 5
// 399.478 us; speedup vs baseline: 1.3143x; 1.3143x over previous
//
#include <hip/hip_runtime.h>
#include <hip/hip_bf16.h>

#define HD 128
#define NEG_SLOPE 0.2f

typedef __attribute__((ext_vector_type(8))) short short8;
typedef __attribute__((ext_vector_type(4))) float f32x4;

__device__ __forceinline__ float lrelu(float x) {
    return x > 0.f ? x : NEG_SLOPE * x;
}
__device__ __forceinline__ ushort f2bf(float f) {
    __hip_bfloat16 h = __float2bfloat16(f);
    return *(ushort*)&h;
}
__device__ __forceinline__ float bflo(unsigned u) { return __uint_as_float(u << 16); }
__device__ __forceinline__ float bfhi(unsigned u) { return __uint_as_float(u & 0xffff0000u); }

// ---------- fused prep: v-vectors + Wt (bf16 transpose) + zero counts ----------
__global__ void k_prep(const float* __restrict__ Ws, const float* __restrict__ Wd,
                       const float* __restrict__ a_s, const float* __restrict__ a_d,
                       float* __restrict__ v, ushort* __restrict__ Wt,
                       int* __restrict__ counts, int nTot) {
    int t = blockIdx.x * blockDim.x + threadIdx.x;
    if (t < nTot) counts[t] = 0;
    if (t < 768) {
        int c = t >> 8;
        int sd = (t >> 7) & 1;
        int d = t & (HD - 1);
        const float* W = sd ? Wd : Ws;
        const float* a = sd ? a_d : a_s;
        const float* Wrow = W + ((size_t)c * HD + d) * HD;
        const float* av = a + c * HD;
        float s = 0.f;
        for (int h = 0; h < HD; h++) s += Wrow[h] * av[h];
        v[t] = s;
    }
    int u = t - 768;
    if (u >= 0 && u < 3 * HD * HD) {
        int c = u >> 14;
        int r = u & 16383;
        int n = r >> 7, k = r & 127;
        Wt[u] = f2bf(Ws[((size_t)c << 14) + k * HD + n]);
    }
}

// ---------- alpha[n] = x[n].v[slot] (<=4 slots) + optional bf16 copy of x ----------
template<bool CVT>
__global__ void k_alpha(const float* __restrict__ x, int N,
                        const float* __restrict__ v,
                        int i0, int i1, int i2, int i3,
                        float* __restrict__ o0, float* __restrict__ o1,
                        float* __restrict__ o2, float* __restrict__ o3, int nv,
                        unsigned* __restrict__ xb) {
    int lane = threadIdx.x & 63;
    int wid = (int)(((long long)blockIdx.x * blockDim.x + threadIdx.x) >> 6);
    int nwaves = (gridDim.x * blockDim.x) >> 6;
    float2 z = make_float2(0.f, 0.f);
    float2 vv0 = *(const float2*)&v[i0 * HD + lane * 2];
    float2 vv1 = (nv > 1) ? *(const float2*)&v[i1 * HD + lane * 2] : z;
    float2 vv2 = (nv > 2) ? *(const float2*)&v[i2 * HD + lane * 2] : z;
    float2 vv3 = (nv > 3) ? *(const float2*)&v[i3 * HD + lane * 2] : z;
    for (int n = wid; n < N; n += nwaves) {
        float2 xv = *(const float2*)&x[(long long)n * HD + lane * 2];
        if (CVT)
            xb[(size_t)n * 64 + lane] = (unsigned)f2bf(xv.x) | ((unsigned)f2bf(xv.y) << 16);
        float s0 = xv.x * vv0.x + xv.y * vv0.y;
        float s1 = xv.x * vv1.x + xv.y * vv1.y;
        float s2 = xv.x * vv2.x + xv.y * vv2.y;
        float s3 = xv.x * vv3.x + xv.y * vv3.y;
        #pragma unroll
        for (int off = 32; off; off >>= 1) {
            s0 += __shfl_xor(s0, off, 64);
            s1 += __shfl_xor(s1, off, 64);
            s2 += __shfl_xor(s2, off, 64);
            s3 += __shfl_xor(s3, off, 64);
        }
        if (lane == 0) {
            o0[n] = s0;
            if (nv > 1) o1[n] = s1;
            if (nv > 2) o2[n] = s2;
            if (nv > 3) o3[n] = s3;
        }
    }
}

// ---------- H16 = A * Wt^T (MFMA), A fp32 (cvt in-kernel) or pre-packed bf16 ----------
template<bool BF16IN>
__global__ __launch_bounds__(256) void k_gemm_mfma(const float* __restrict__ X,
                                                   const unsigned* __restrict__ XB,
                                                   const ushort* __restrict__ Wt,
                                                   ushort* __restrict__ H16, int nrows) {
    int tid = threadIdx.x;
    int lane = tid & 63;
    int wv = tid >> 6;
    int m = lane & 15;
    int kb = lane >> 4;
    long long row0 = (long long)blockIdx.x * 64 + wv * 16;
    long long ar = row0 + m;
    if (ar >= nrows) ar = nrows - 1;               // clamped read, store guarded
    const float* aptr = X ? (X + ar * HD + kb * 8) : nullptr;
    const ushort* abptr = BF16IN ? ((const ushort*)XB + ar * HD + kb * 8) : nullptr;
    const ushort* bptr = Wt + (size_t)m * HD + kb * 8;

    f32x4 acc[8];
    #pragma unroll
    for (int t = 0; t < 8; t++) acc[t] = (f32x4){0.f, 0.f, 0.f, 0.f};

    #pragma unroll
    for (int ks = 0; ks < 4; ks++) {
        short8 af;
        if (BF16IN) {
            af = *(const short8*)(abptr + ks * 32);
        } else {
            float4 a0 = *(const float4*)(aptr + ks * 32);
            float4 a1 = *(const float4*)(aptr + ks * 32 + 4);
            af[0] = (short)f2bf(a0.x); af[1] = (short)f2bf(a0.y);
            af[2] = (short)f2bf(a0.z); af[3] = (short)f2bf(a0.w);
            af[4] = (short)f2bf(a1.x); af[5] = (short)f2bf(a1.y);
            af[6] = (short)f2bf(a1.z); af[7] = (short)f2bf(a1.w);
        }
        #pragma unroll
        for (int t = 0; t < 8; t++) {
            short8 bf = *(const short8*)(bptr + (size_t)t * 16 * HD + ks * 32);
            acc[t] = __builtin_amdgcn_mfma_f32_16x16x32_bf16(af, bf, acc[t], 0, 0, 0);
        }
    }
    int rb = (lane >> 4) * 4;
    #pragma unroll
    for (int t = 0; t < 8; t++) {
        #pragma unroll
        for (int j = 0; j < 4; j++) {
            long long r = row0 + rb + j;
            if (r < nrows) H16[r * HD + t * 16 + m] = f2bf(acc[t][j]);
        }
    }
}

// ---------- CSR build (fused over 3 relations) ----------
// rank trick: the histogram atomic's RETURN VALUE is the edge's rank within its
// dst segment, stored coalesced; the later fill pass is then atomic-free.
__global__ void k_hist3(const int* __restrict__ d0, const int* __restrict__ d1,
                        const int* __restrict__ d2, int* __restrict__ counts,
                        ushort* __restrict__ rank16, int E, int off1, int off2) {
    int t = blockIdx.x * blockDim.x + threadIdx.x;
    if (t >= 3 * E) return;
    int gd;
    if (t < E)           gd = d0[t];
    else if (t < 2 * E)  gd = off1 + d1[t - E];
    else                 gd = off2 + d2[t - 2 * E];
    rank16[t] = (ushort)atomicAdd(&counts[gd], 1);
}

__global__ void k_chunksum(const int* __restrict__ counts, int* __restrict__ chunkSum, int n) {
    __shared__ int sh[256];
    int i = blockIdx.x * 256 + threadIdx.x;
    sh[threadIdx.x] = (i < n) ? counts[i] : 0;
    __syncthreads();
    for (int off = 128; off; off >>= 1) {
        if (threadIdx.x < off) sh[threadIdx.x] += sh[threadIdx.x + off];
        __syncthreads();
    }
    if (threadIdx.x == 0) chunkSum[blockIdx.x] = sh[0];
}

__global__ void k_scanchunk(const int* __restrict__ chunkSum, int* __restrict__ chunkOff, int nChunk) {
    __shared__ int sh[1024];
    int t = threadIdx.x;
    int v = (t < nChunk) ? chunkSum[t] : 0;
    sh[t] = v;
    __syncthreads();
    for (int off = 1; off < 1024; off <<= 1) {
        int add = (t >= off) ? sh[t - off] : 0;
        __syncthreads();
        sh[t] += add;
        __syncthreads();
    }
    if (t < nChunk) chunkOff[t] = sh[t] - v; // exclusive
}

__global__ void k_rowstart(const int* __restrict__ counts, const int* __restrict__ chunkOff,
                           int* __restrict__ rowStart, int n) {
    __shared__ int sh[256];
    int i = blockIdx.x * 256 + threadIdx.x;
    int t = threadIdx.x;
    int v = (i < n) ? counts[i] : 0;
    sh[t] = v;
    __syncthreads();
    for (int off = 1; off < 256; off <<= 1) {
        int add = (t >= off) ? sh[t - off] : 0;
        __syncthreads();
        sh[t] += add;
        __syncthreads();
    }
    if (i < n) rowStart[i] = chunkOff[blockIdx.x] + sh[t] - v;
}

// ---------- atomic-free CSR fill: eSrc[rowStart[gd] + rank[e]] = src[e] ----------
__global__ void k_fill3(const int* __restrict__ s0, const int* __restrict__ d0,
                        const int* __restrict__ s1, const int* __restrict__ d1,
                        const int* __restrict__ s2, const int* __restrict__ d2,
                        const int* __restrict__ rowStart, const ushort* __restrict__ rank16,
                        int* __restrict__ eSrc, int E, int off1, int off2) {
    int t = blockIdx.x * blockDim.x + threadIdx.x;
    if (t >= 3 * E) return;
    int sv, gd;
    if (t < E)          { sv = s0[t];        gd = d0[t]; }
    else if (t < 2 * E) { int e = t - E;     sv = s1[e]; gd = off1 + d1[e]; }
    else                { int e = t - 2 * E; sv = s2[e]; gd = off2 + d2[e]; }
    eSrc[rowStart[gd] + rank16[t]] = sv;
}

// ---------- fused per-dst softmax + 4-edge-parallel gather + bias/relu epilogue ----
// MODE 0: out = biasA+biasB + acc           (conv0, artwork block, first writer)
// MODE 1: out = relu(biasA + acc)           (conv1, artist block, only writer)
// MODE 2: out = relu(out + acc)             (conv2, artwork block, last writer)
template<int MODE>
__global__ __launch_bounds__(256) void k_agg(const int* __restrict__ eSrc,
                                             const int* __restrict__ rowStart,
                                             const int* __restrict__ counts,
                                             const float* __restrict__ as_,
                                             const float* __restrict__ ad_,
                                             const ushort* __restrict__ hs,
                                             const float* __restrict__ biasA,
                                             const float* __restrict__ biasB,
                                             float* __restrict__ out, int Nd) {
    int lane = threadIdx.x & 63;
    int d = (int)(((long long)blockIdx.x * blockDim.x + threadIdx.x) >> 6);
    if (d >= Nd) return;
    int sub = lane >> 4;        // edge slot 0..3
    int fl = lane & 15;         // feature block: features fl*8 .. fl*8+7
    int dg = counts[d];

    float acc[8];
    #pragma unroll
    for (int k = 0; k < 8; k++) acc[k] = 0.f;

    if (dg > 0) {
        int base = rowStart[d];
        float ad = ad_[d];
        if (dg <= 64) {
            int s = 0;
            float av = -1e30f;
            if (lane < dg) { s = eSrc[base + lane]; av = lrelu(as_[s] + ad); }
            float mm = av;
            #pragma unroll
            for (int off = 32; off; off >>= 1) mm = fmaxf(mm, __shfl_xor(mm, off, 64));
            float w = (lane < dg) ? __expf(av - mm) : 0.f;
            float den = w;
            #pragma unroll
            for (int off = 32; off; off >>= 1) den += __shfl_xor(den, off, 64);
            w *= (1.f / den);   // den >= 1 (max edge contributes exp(0))
            for (int j0 = 0; j0 < dg; j0 += 4) {
                int idx = j0 + sub;
                float wj = __shfl(w, idx, 64);   // 0 for idx >= dg
                int sj = __shfl(s, idx, 64);     // 0 for idx >= dg (safe row)
                uint4 u = *(const uint4*)((const unsigned*)hs + ((size_t)sj * HD + fl * 8) / 2);
                acc[0] += wj * bflo(u.x); acc[1] += wj * bfhi(u.x);
                acc[2] += wj * bflo(u.y); acc[3] += wj * bfhi(u.y);
                acc[4] += wj * bflo(u.z); acc[5] += wj * bfhi(u.z);
                acc[6] += wj * bflo(u.w); acc[7] += wj * bfhi(u.w);
            }
        } else {
            float mm = -1e30f;
            for (int i = lane; i < dg; i += 64)
                mm = fmaxf(mm, lrelu(as_[eSrc[base + i]] + ad));
            #pragma unroll
            for (int off = 32; off; off >>= 1) mm = fmaxf(mm, __shfl_xor(mm, off, 64));
            float den = 0.f;
            for (int i = lane; i < dg; i += 64)
                den += __expf(lrelu(as_[eSrc[base + i]] + ad) - mm);
            #pragma unroll
            for (int off = 32; off; off >>= 1) den += __shfl_xor(den, off, 64);
            float inv = 1.f / den;
            for (int c0 = 0; c0 < dg; c0 += 64) {
                int n = min(64, dg - c0);
                int s = 0; float w = 0.f;
                if (lane < n) {
                    s = eSrc[base + c0 + lane];
                    w = __expf(lrelu(as_[s] + ad) - mm) * inv;
                }
                for (int j0 = 0; j0 < n; j0 += 4) {
                    int idx = j0 + sub;
                    float wj = __shfl(w, idx, 64);
                    int sj = __shfl(s, idx, 64);
                    uint4 u = *(const uint4*)((const unsigned*)hs + ((size_t)sj * HD + fl * 8) / 2);
                    acc[0] += wj * bflo(u.x); acc[1] += wj * bfhi(u.x);
                    acc[2] += wj * bflo(u.y); acc[3] += wj * bfhi(u.y);
                    acc[4] += wj * bflo(u.z); acc[5] += wj * bfhi(u.z);
                    acc[6] += wj * bflo(u.w); acc[7] += wj * bfhi(u.w);
                }
            }
        }
        // fold the 4 edge slots: lanes with same fl sum up
        #pragma unroll
        for (int k = 0; k < 8; k++) {
            acc[k] += __shfl_xor(acc[k], 16, 64);
            acc[k] += __shfl_xor(acc[k], 32, 64);
        }
    }

    if (lane < 16) {
        float* orow = out + (size_t)d * HD + fl * 8;
        float vals[8];
        #pragma unroll
        for (int k = 0; k < 8; k++) {
            float bv;
            if (MODE == 0)      bv = biasA[fl * 8 + k] + biasB[fl * 8 + k];
            else if (MODE == 1) bv = biasA[fl * 8 + k];
            else                bv = orow[k];
            float o = bv + acc[k];
            vals[k] = (MODE >= 1) ? fmaxf(o, 0.f) : o;
        }
        *(float4*)&orow[0] = make_float4(vals[0], vals[1], vals[2], vals[3]);
        *(float4*)&orow[4] = make_float4(vals[4], vals[5], vals[6], vals[7]);
    }
}

extern "C" void kernel_launch(void* const* d_in, const int* in_sizes, int n_in,
                              void* d_out, int out_size, void* d_ws, size_t ws_size,
                              hipStream_t stream) {
    const float* x_artist  = (const float*)d_in[0];
    const float* x_artwork = (const float*)d_in[1];
    const int* srcA[3] = {(const int*)d_in[2], (const int*)d_in[4], (const int*)d_in[6]};
    const int* dstA[3] = {(const int*)d_in[3], (const int*)d_in[5], (const int*)d_in[7]};
    const float* Ws  = (const float*)d_in[8];
    const float* Wd  = (const float*)d_in[9];
    const float* a_s = (const float*)d_in[10];
    const float* a_d = (const float*)d_in[11];
    const float* b   = (const float*)d_in[12];
    float* out = (float*)d_out;

    const int Na = in_sizes[0] / HD;
    const int Nw = in_sizes[1] / HD;
    const int E  = in_sizes[2];
    const int nTot = Nw + Na + Nw;              // concatenated dst-node space
    const int nChunk = (nTot + 255) / 256;      // <= 1024 required

    // ---- workspace carve-up (4-byte words; all chunks 16B-aligned) ----
    float* ws = (float*)d_ws;
    size_t off = 0;
    float* v   = ws + off;  off += 768;
    float* as0 = ws + off;  off += Na;
    float* ad0 = ws + off;  off += Nw;
    float* as1 = ws + off;  off += Nw;
    float* ad1 = ws + off;  off += Na;
    float* as2 = ws + off;  off += Nw;
    float* ad2 = ws + off;  off += Nw;
    int* counts   = (int*)(ws + off); off += nTot;
    int* chunkSum = (int*)(ws + off); off += 1024;
    int* chunkOff = (int*)(ws + off); off += 1024;
    int* rowStart = (int*)(ws + off); off += nTot;
    int* eSrc     = (int*)(ws + off); off += (size_t)3 * E;
    ushort* Wt    = (ushort*)(ws + off); off += (3 * HD * HD) / 2;
    unsigned* xbW = (unsigned*)(ws + off); off += (size_t)Nw * (HD / 2);   // bf16 x_artwork
    ushort* hs16  = (ushort*)(ws + off); off += (size_t)Nw * HD / 2;
    if (ws_size < off * sizeof(float) || nChunk > 1024) return;

    // rank16 aliases hs16: dead after k_fill3, hs16 written only by later GEMMs.
    // hs16 holds Nw*HD ushorts (12.8M) >= 3E (1.92M) rank entries.
    ushort* rank16 = hs16;

    // per-conv metadata
    const float* asP[3]   = {as0, as1, as2};
    const float* adP[3]   = {ad0, ad1, ad2};
    const int statOff[3]  = {0, Nw, Nw + Na};
    const int nsrc[3]     = {Na, Nw, Nw};
    const int ndst[3]     = {Nw, Na, Nw};
    const long long outBase[3] = {(long long)Na * HD, 0, (long long)Na * HD};

    const int B = 256;
    int prepN = nTot > (768 + 3 * HD * HD) ? nTot : (768 + 3 * HD * HD);

    k_prep<<<(prepN + B - 1) / B, B, 0, stream>>>(Ws, Wd, a_s, a_d, v, Wt, counts, nTot);

    // alphas: artist pass (slots vs0=0, vd1=3), artwork pass (vd0=1, vs1=2, vs2=4, vd2=5) + bf16 cvt
    k_alpha<false><<<1024, B, 0, stream>>>(x_artist, Na, v, 0, 3, 0, 0,
                                           as0, ad1, nullptr, nullptr, 2, nullptr);
    k_alpha<true><<<1024, B, 0, stream>>>(x_artwork, Nw, v, 1, 2, 4, 5,
                                          ad0, as1, as2, ad2, 4, xbW);

    // CSR build over concatenated dst space (rank trick -> atomic-free fill)
    k_hist3<<<(3 * E + B - 1) / B, B, 0, stream>>>(dstA[0], dstA[1], dstA[2], counts,
                                                   rank16, E, statOff[1], statOff[2]);
    k_chunksum<<<nChunk, B, 0, stream>>>(counts, chunkSum, nTot);
    k_scanchunk<<<1, 1024, 0, stream>>>(chunkSum, chunkOff, nChunk);
    k_rowstart<<<nChunk, B, 0, stream>>>(counts, chunkOff, rowStart, nTot);
    k_fill3<<<(3 * E + B - 1) / B, B, 0, stream>>>(srcA[0], dstA[0], srcA[1], dstA[1],
                                                   srcA[2], dstA[2], rowStart, rank16,
                                                   eSrc, E, statOff[1], statOff[2]);

    // per conv: hs GEMM (bf16 out, shared scratch) then gather-aggregate into d_out
    for (int c = 0; c < 3; c++) {
        if (c == 0)
            k_gemm_mfma<false><<<(nsrc[c] + 63) / 64, B, 0, stream>>>(
                x_artist, nullptr, Wt + (size_t)c * HD * HD, hs16, nsrc[c]);
        else
            k_gemm_mfma<true><<<(nsrc[c] + 63) / 64, B, 0, stream>>>(
                nullptr, xbW, Wt + (size_t)c * HD * HD, hs16, nsrc[c]);
        int nblk = (ndst[c] + 3) / 4; // 4 waves per 256-thread block, wave per dst
        if (c == 0)
            k_agg<0><<<nblk, B, 0, stream>>>(eSrc, rowStart + statOff[c], counts + statOff[c],
                                             asP[c], adP[c], hs16, b, b + 2 * HD,
                                             out + outBase[c], ndst[c]);
        else if (c == 1)
            k_agg<1><<<nblk, B, 0, stream>>>(eSrc, rowStart + statOff[c], counts + statOff[c],
                                             asP[c], adP[c], hs16, b + HD, nullptr,
                                             out + outBase[c], ndst[c]);
        else
            k_agg<2><<<nblk, B, 0, stream>>>(eSrc, rowStart + statOff[c], counts + statOff[c],
                                             asP[c], adP[c], hs16, nullptr, nullptr,
                                             out + outBase[c], ndst[c]);
    }
}

// Round 6
// 364.400 us; speedup vs baseline: 1.4408x; 1.0963x over previous
//
#include <hip/hip_runtime.h>
#include <hip/hip_bf16.h>

#define HD 128
#define NEG_SLOPE 0.2f

typedef __attribute__((ext_vector_type(8))) short short8;
typedef __attribute__((ext_vector_type(4))) float f32x4;

__device__ __forceinline__ float lrelu(float x) {
    return x > 0.f ? x : NEG_SLOPE * x;
}
__device__ __forceinline__ ushort f2bf(float f) {
    __hip_bfloat16 h = __float2bfloat16(f);
    return *(ushort*)&h;
}
__device__ __forceinline__ float bflo(unsigned u) { return __uint_as_float(u << 16); }
__device__ __forceinline__ float bfhi(unsigned u) { return __uint_as_float(u & 0xffff0000u); }

// ---------- fused prep: v-vectors + Wt (bf16 transpose) + zero counts ----------
__global__ void k_prep(const float* __restrict__ Ws, const float* __restrict__ Wd,
                       const float* __restrict__ a_s, const float* __restrict__ a_d,
                       float* __restrict__ v, ushort* __restrict__ Wt,
                       int* __restrict__ counts, int nTot) {
    int t = blockIdx.x * blockDim.x + threadIdx.x;
    if (t < nTot) counts[t] = 0;
    if (t < 768) {
        int c = t >> 8;
        int sd = (t >> 7) & 1;
        int d = t & (HD - 1);
        const float* W = sd ? Wd : Ws;
        const float* a = sd ? a_d : a_s;
        const float* Wrow = W + ((size_t)c * HD + d) * HD;
        const float* av = a + c * HD;
        float s = 0.f;
        for (int h = 0; h < HD; h++) s += Wrow[h] * av[h];
        v[t] = s;
    }
    int u = t - 768;
    if (u >= 0 && u < 3 * HD * HD) {
        int c = u >> 14;
        int r = u & 16383;
        int n = r >> 7, k = r & 127;
        Wt[u] = f2bf(Ws[((size_t)c << 14) + k * HD + n]);
    }
}

// ---------- fused alphas: artist rows (2 dots) + artwork rows (4 dots) ----------
__global__ void k_alpha2(const float* __restrict__ xa, int Na,
                         const float* __restrict__ xw, int Nw,
                         const float* __restrict__ v,
                         float* __restrict__ as0, float* __restrict__ ad1,
                         float* __restrict__ ad0, float* __restrict__ as1,
                         float* __restrict__ as2, float* __restrict__ ad2) {
    int lane = threadIdx.x & 63;
    int wid = (int)(((long long)blockIdx.x * blockDim.x + threadIdx.x) >> 6);
    int nwaves = (gridDim.x * blockDim.x) >> 6;
    float2 v0 = *(const float2*)&v[0 * HD + lane * 2];
    float2 v1 = *(const float2*)&v[1 * HD + lane * 2];
    float2 v2 = *(const float2*)&v[2 * HD + lane * 2];
    float2 v3 = *(const float2*)&v[3 * HD + lane * 2];
    float2 v4 = *(const float2*)&v[4 * HD + lane * 2];
    float2 v5 = *(const float2*)&v[5 * HD + lane * 2];
    int total = Na + Nw;
    for (int n = wid; n < total; n += nwaves) {
        if (n < Na) {
            float2 xv = *(const float2*)&xa[(size_t)n * HD + lane * 2];
            float s0 = xv.x * v0.x + xv.y * v0.y;
            float s3 = xv.x * v3.x + xv.y * v3.y;
            #pragma unroll
            for (int off = 32; off; off >>= 1) {
                s0 += __shfl_xor(s0, off, 64);
                s3 += __shfl_xor(s3, off, 64);
            }
            if (lane == 0) { as0[n] = s0; ad1[n] = s3; }
        } else {
            int m = n - Na;
            float2 xv = *(const float2*)&xw[(size_t)m * HD + lane * 2];
            float s1 = xv.x * v1.x + xv.y * v1.y;
            float s2 = xv.x * v2.x + xv.y * v2.y;
            float s4 = xv.x * v4.x + xv.y * v4.y;
            float s5 = xv.x * v5.x + xv.y * v5.y;
            #pragma unroll
            for (int off = 32; off; off >>= 1) {
                s1 += __shfl_xor(s1, off, 64);
                s2 += __shfl_xor(s2, off, 64);
                s4 += __shfl_xor(s4, off, 64);
                s5 += __shfl_xor(s5, off, 64);
            }
            if (lane == 0) { ad0[m] = s1; as1[m] = s2; as2[m] = s4; ad2[m] = s5; }
        }
    }
}

// ---------- H16[nrows x 128] (bf16) = X(fp32) * Wt^T, MFMA ----------
__global__ __launch_bounds__(256) void k_gemm_mfma(const float* __restrict__ X,
                                                   const ushort* __restrict__ Wt,
                                                   ushort* __restrict__ H16, int nrows) {
    int tid = threadIdx.x;
    int lane = tid & 63;
    int wv = tid >> 6;
    int m = lane & 15;
    int kb = lane >> 4;
    long long row0 = (long long)blockIdx.x * 64 + wv * 16;
    long long ar = row0 + m;
    if (ar >= nrows) ar = nrows - 1;               // clamped read, store guarded
    const float* aptr = X + ar * HD + kb * 8;
    const ushort* bptr = Wt + (size_t)m * HD + kb * 8;

    f32x4 acc[8];
    #pragma unroll
    for (int t = 0; t < 8; t++) acc[t] = (f32x4){0.f, 0.f, 0.f, 0.f};

    #pragma unroll
    for (int ks = 0; ks < 4; ks++) {
        float4 a0 = *(const float4*)(aptr + ks * 32);
        float4 a1 = *(const float4*)(aptr + ks * 32 + 4);
        short8 af;
        af[0] = (short)f2bf(a0.x); af[1] = (short)f2bf(a0.y);
        af[2] = (short)f2bf(a0.z); af[3] = (short)f2bf(a0.w);
        af[4] = (short)f2bf(a1.x); af[5] = (short)f2bf(a1.y);
        af[6] = (short)f2bf(a1.z); af[7] = (short)f2bf(a1.w);
        #pragma unroll
        for (int t = 0; t < 8; t++) {
            short8 bf = *(const short8*)(bptr + (size_t)t * 16 * HD + ks * 32);
            acc[t] = __builtin_amdgcn_mfma_f32_16x16x32_bf16(af, bf, acc[t], 0, 0, 0);
        }
    }
    int rb = (lane >> 4) * 4;
    #pragma unroll
    for (int t = 0; t < 8; t++) {
        #pragma unroll
        for (int j = 0; j < 4; j++) {
            long long r = row0 + rb + j;
            if (r < nrows) H16[r * HD + t * 16 + m] = f2bf(acc[t][j]);
        }
    }
}

// ---------- CSR build: hist + in-segment rank (atomic return), fused 3 relations ----
__global__ void k_hist3(const int* __restrict__ d0, const int* __restrict__ d1,
                        const int* __restrict__ d2, int* __restrict__ counts,
                        ushort* __restrict__ rank16, int E, int off1, int off2) {
    int t = blockIdx.x * blockDim.x + threadIdx.x;
    if (t >= 3 * E) return;
    int gd;
    if (t < E)           gd = d0[t];
    else if (t < 2 * E)  gd = off1 + d1[t - E];
    else                 gd = off2 + d2[t - 2 * E];
    rank16[t] = (ushort)atomicAdd(&counts[gd], 1);
}

__global__ void k_chunksum(const int* __restrict__ counts, int* __restrict__ chunkSum, int n) {
    __shared__ int sh[256];
    int i = blockIdx.x * 256 + threadIdx.x;
    sh[threadIdx.x] = (i < n) ? counts[i] : 0;
    __syncthreads();
    for (int off = 128; off; off >>= 1) {
        if (threadIdx.x < off) sh[threadIdx.x] += sh[threadIdx.x + off];
        __syncthreads();
    }
    if (threadIdx.x == 0) chunkSum[blockIdx.x] = sh[0];
}

__global__ void k_scanchunk(const int* __restrict__ chunkSum, int* __restrict__ chunkOff, int nChunk) {
    __shared__ int sh[1024];
    int t = threadIdx.x;
    int v = (t < nChunk) ? chunkSum[t] : 0;
    sh[t] = v;
    __syncthreads();
    for (int off = 1; off < 1024; off <<= 1) {
        int add = (t >= off) ? sh[t - off] : 0;
        __syncthreads();
        sh[t] += add;
        __syncthreads();
    }
    if (t < nChunk) chunkOff[t] = sh[t] - v; // exclusive
}

__global__ void k_rowstart(const int* __restrict__ counts, const int* __restrict__ chunkOff,
                           int* __restrict__ rowStart, int n) {
    __shared__ int sh[256];
    int i = blockIdx.x * 256 + threadIdx.x;
    int t = threadIdx.x;
    int v = (i < n) ? counts[i] : 0;
    sh[t] = v;
    __syncthreads();
    for (int off = 1; off < 256; off <<= 1) {
        int add = (t >= off) ? sh[t - off] : 0;
        __syncthreads();
        sh[t] += add;
        __syncthreads();
    }
    if (i < n) rowStart[i] = chunkOff[blockIdx.x] + sh[t] - v;
}

// ---------- atomic-free CSR fill: ePair[slot] = {src, alpha_s[src]} ----------
__global__ void k_fill3(const int* __restrict__ s0, const int* __restrict__ d0,
                        const int* __restrict__ s1, const int* __restrict__ d1,
                        const int* __restrict__ s2, const int* __restrict__ d2,
                        const float* __restrict__ as0, const float* __restrict__ as1,
                        const float* __restrict__ as2,
                        const int* __restrict__ rowStart, const ushort* __restrict__ rank16,
                        int2* __restrict__ ePair, int E, int off1, int off2) {
    int t = blockIdx.x * blockDim.x + threadIdx.x;
    if (t >= 3 * E) return;
    int sv, gd;
    const float* A;
    if (t < E)          { sv = s0[t];        gd = d0[t];        A = as0; }
    else if (t < 2 * E) { int e = t - E;     sv = s1[e]; gd = off1 + d1[e]; A = as1; }
    else                { int e = t - 2 * E; sv = s2[e]; gd = off2 + d2[e]; A = as2; }
    ePair[rowStart[gd] + rank16[t]] = make_int2(sv, __float_as_int(A[sv]));
}

// ---------- segment softmax + 4-edge-parallel gather into acc[8] ----------
// Common path (dg<=64): caller has preloaded this lane's {src,alpha} pair.
__device__ __forceinline__ void seg_accum(int2 p, int dg, int base, float adv,
                                          const int2* __restrict__ ePair,
                                          const ushort* __restrict__ hs,
                                          int lane, int sub, int fl, float acc[8]) {
    if (dg <= 0) return;
    if (dg <= 64) {
        float av = (lane < dg) ? lrelu(__int_as_float(p.y) + adv) : -1e30f;
        float mm = av;
        #pragma unroll
        for (int off = 32; off; off >>= 1) mm = fmaxf(mm, __shfl_xor(mm, off, 64));
        float w = (lane < dg) ? __expf(av - mm) : 0.f;
        float den = w;
        #pragma unroll
        for (int off = 32; off; off >>= 1) den += __shfl_xor(den, off, 64);
        w *= (1.f / den);   // den >= 1 (max edge contributes exp(0))
        int s = (lane < dg) ? p.x : 0;
        for (int j0 = 0; j0 < dg; j0 += 4) {
            int idx = j0 + sub;
            float wj = __shfl(w, idx, 64);
            int sj = __shfl(s, idx, 64);
            uint4 u = *(const uint4*)((const unsigned*)hs + ((size_t)sj * HD + fl * 8) / 2);
            acc[0] += wj * bflo(u.x); acc[1] += wj * bfhi(u.x);
            acc[2] += wj * bflo(u.y); acc[3] += wj * bfhi(u.y);
            acc[4] += wj * bflo(u.z); acc[5] += wj * bfhi(u.z);
            acc[6] += wj * bflo(u.w); acc[7] += wj * bfhi(u.w);
        }
    } else {
        float mm = -1e30f;
        for (int i = lane; i < dg; i += 64) {
            int2 q = ePair[base + i];
            mm = fmaxf(mm, lrelu(__int_as_float(q.y) + adv));
        }
        #pragma unroll
        for (int off = 32; off; off >>= 1) mm = fmaxf(mm, __shfl_xor(mm, off, 64));
        float den = 0.f;
        for (int i = lane; i < dg; i += 64) {
            int2 q = ePair[base + i];
            den += __expf(lrelu(__int_as_float(q.y) + adv) - mm);
        }
        #pragma unroll
        for (int off = 32; off; off >>= 1) den += __shfl_xor(den, off, 64);
        float inv = 1.f / den;
        for (int c0 = 0; c0 < dg; c0 += 64) {
            int n = min(64, dg - c0);
            int s = 0; float w = 0.f;
            if (lane < n) {
                int2 q = ePair[base + c0 + lane];
                s = q.x;
                w = __expf(lrelu(__int_as_float(q.y) + adv) - mm) * inv;
            }
            for (int j0 = 0; j0 < n; j0 += 4) {
                int idx = j0 + sub;
                float wj = __shfl(w, idx, 64);
                int sj = __shfl(s, idx, 64);
                uint4 u = *(const uint4*)((const unsigned*)hs + ((size_t)sj * HD + fl * 8) / 2);
                acc[0] += wj * bflo(u.x); acc[1] += wj * bfhi(u.x);
                acc[2] += wj * bflo(u.y); acc[3] += wj * bfhi(u.y);
                acc[4] += wj * bflo(u.z); acc[5] += wj * bfhi(u.z);
                acc[6] += wj * bflo(u.w); acc[7] += wj * bfhi(u.w);
            }
        }
    }
}

// ---------- fused conv0+conv2 aggregate into artwork block: relu(b0+b2+accA+accB) ----
__global__ __launch_bounds__(256) void k_agg02(const int2* __restrict__ ePair,
        const int* __restrict__ rowStart, const int* __restrict__ counts,
        const float* __restrict__ ad0_, const float* __restrict__ ad2_,
        const ushort* __restrict__ hs0, const ushort* __restrict__ hs2,
        const float* __restrict__ b0, const float* __restrict__ b2,
        float* __restrict__ out, int Nw, int offR2) {
    int lane = threadIdx.x & 63;
    int d = (int)(((long long)blockIdx.x * blockDim.x + threadIdx.x) >> 6);
    if (d >= Nw) return;
    int sub = lane >> 4, fl = lane & 15;

    int dgA = counts[d],         bA = rowStart[d];
    int dgB = counts[offR2 + d], bB = rowStart[offR2 + d];
    float aA = ad0_[d], aB = ad2_[d];
    int2 pA = make_int2(0, 0), pB = make_int2(0, 0);
    if (dgA > 0 && dgA <= 64 && lane < dgA) pA = ePair[bA + lane];
    if (dgB > 0 && dgB <= 64 && lane < dgB) pB = ePair[bB + lane];

    float acc[8];
    #pragma unroll
    for (int k = 0; k < 8; k++) acc[k] = 0.f;
    seg_accum(pA, dgA, bA, aA, ePair, hs0, lane, sub, fl, acc);
    seg_accum(pB, dgB, bB, aB, ePair, hs2, lane, sub, fl, acc);

    #pragma unroll
    for (int k = 0; k < 8; k++) {
        acc[k] += __shfl_xor(acc[k], 16, 64);
        acc[k] += __shfl_xor(acc[k], 32, 64);
    }
    if (lane < 16) {
        float* orow = out + (size_t)d * HD + fl * 8;
        float vals[8];
        #pragma unroll
        for (int k = 0; k < 8; k++)
            vals[k] = fmaxf(b0[fl * 8 + k] + b2[fl * 8 + k] + acc[k], 0.f);
        *(float4*)&orow[0] = make_float4(vals[0], vals[1], vals[2], vals[3]);
        *(float4*)&orow[4] = make_float4(vals[4], vals[5], vals[6], vals[7]);
    }
}

// ---------- conv1 aggregate into artist block, 2 dsts per wave: relu(b1+acc) ----------
__global__ __launch_bounds__(256) void k_agg1(const int2* __restrict__ ePair,
        const int* __restrict__ rowStart, const int* __restrict__ counts,
        const float* __restrict__ ad_, const ushort* __restrict__ hs,
        const float* __restrict__ bias, float* __restrict__ out, int Nd) {
    int lane = threadIdx.x & 63;
    int w = (int)(((long long)blockIdx.x * blockDim.x + threadIdx.x) >> 6);
    int d0 = 2 * w, d1 = 2 * w + 1;
    if (d0 >= Nd) return;
    int sub = lane >> 4, fl = lane & 15;

    int dg0 = counts[d0], b0 = rowStart[d0];
    float a0 = ad_[d0];
    int dg1 = 0, b1 = 0; float a1 = 0.f;
    if (d1 < Nd) { dg1 = counts[d1]; b1 = rowStart[d1]; a1 = ad_[d1]; }
    int2 p0 = make_int2(0, 0), p1 = make_int2(0, 0);
    if (dg0 > 0 && dg0 <= 64 && lane < dg0) p0 = ePair[b0 + lane];
    if (dg1 > 0 && dg1 <= 64 && lane < dg1) p1 = ePair[b1 + lane];

    float acc0[8], acc1[8];
    #pragma unroll
    for (int k = 0; k < 8; k++) { acc0[k] = 0.f; acc1[k] = 0.f; }
    seg_accum(p0, dg0, b0, a0, ePair, hs, lane, sub, fl, acc0);
    seg_accum(p1, dg1, b1, a1, ePair, hs, lane, sub, fl, acc1);

    #pragma unroll
    for (int k = 0; k < 8; k++) {
        acc0[k] += __shfl_xor(acc0[k], 16, 64);
        acc0[k] += __shfl_xor(acc0[k], 32, 64);
        acc1[k] += __shfl_xor(acc1[k], 16, 64);
        acc1[k] += __shfl_xor(acc1[k], 32, 64);
    }
    if (lane < 16) {
        float* orow = out + (size_t)d0 * HD + fl * 8;
        float vals[8];
        #pragma unroll
        for (int k = 0; k < 8; k++)
            vals[k] = fmaxf(bias[fl * 8 + k] + acc0[k], 0.f);
        *(float4*)&orow[0] = make_float4(vals[0], vals[1], vals[2], vals[3]);
        *(float4*)&orow[4] = make_float4(vals[4], vals[5], vals[6], vals[7]);
        if (d1 < Nd) {
            float* orow1 = out + (size_t)d1 * HD + fl * 8;
            #pragma unroll
            for (int k = 0; k < 8; k++)
                vals[k] = fmaxf(bias[fl * 8 + k] + acc1[k], 0.f);
            *(float4*)&orow1[0] = make_float4(vals[0], vals[1], vals[2], vals[3]);
            *(float4*)&orow1[4] = make_float4(vals[4], vals[5], vals[6], vals[7]);
        }
    }
}

extern "C" void kernel_launch(void* const* d_in, const int* in_sizes, int n_in,
                              void* d_out, int out_size, void* d_ws, size_t ws_size,
                              hipStream_t stream) {
    const float* x_artist  = (const float*)d_in[0];
    const float* x_artwork = (const float*)d_in[1];
    const int* srcA[3] = {(const int*)d_in[2], (const int*)d_in[4], (const int*)d_in[6]};
    const int* dstA[3] = {(const int*)d_in[3], (const int*)d_in[5], (const int*)d_in[7]};
    const float* Ws  = (const float*)d_in[8];
    const float* Wd  = (const float*)d_in[9];
    const float* a_s = (const float*)d_in[10];
    const float* a_d = (const float*)d_in[11];
    const float* b   = (const float*)d_in[12];
    float* out = (float*)d_out;

    const int Na = in_sizes[0] / HD;
    const int Nw = in_sizes[1] / HD;
    const int E  = in_sizes[2];
    const int nTot = Nw + Na + Nw;              // concatenated dst-node space
    const int nChunk = (nTot + 255) / 256;      // <= 1024 required

    // ---- workspace carve-up (4-byte words; all chunks 16B-aligned enough) ----
    float* ws = (float*)d_ws;
    size_t off = 0;
    float* v   = ws + off;  off += 768;
    float* as0 = ws + off;  off += Na;
    float* ad0 = ws + off;  off += Nw;
    float* as1 = ws + off;  off += Nw;
    float* ad1 = ws + off;  off += Na;
    float* as2 = ws + off;  off += Nw;
    float* ad2 = ws + off;  off += Nw;
    int* counts   = (int*)(ws + off); off += nTot;
    int* chunkSum = (int*)(ws + off); off += 1024;
    int* chunkOff = (int*)(ws + off); off += 1024;
    int* rowStart = (int*)(ws + off); off += nTot;
    int2* ePair   = (int2*)(ws + off); off += (size_t)2 * 3 * E;
    ushort* Wt    = (ushort*)(ws + off); off += (3 * HD * HD) / 2;
    ushort* hs0   = (ushort*)(ws + off); off += (size_t)Na * HD / 2;   // artist hs (conv0)
    ushort* hs2   = (ushort*)(ws + off); off += (size_t)Nw * HD / 2;   // artwork hs (conv2, then conv1)
    if (ws_size < off * sizeof(float) || nChunk > 1024) return;

    // rank16 aliases hs2: consumed by k_fill3 before gemm writes hs2.
    ushort* rank16 = hs2;

    const int off1 = Nw, off2 = Nw + Na;
    const int B = 256;

    k_prep<<<(nTot + B - 1) / B, B, 0, stream>>>(Ws, Wd, a_s, a_d, v, Wt, counts, nTot);
    k_alpha2<<<1024, B, 0, stream>>>(x_artist, Na, x_artwork, Nw, v,
                                     as0, ad1, ad0, as1, as2, ad2);

    // CSR build over concatenated dst space (rank trick -> atomic-free fill)
    k_hist3<<<(3 * E + B - 1) / B, B, 0, stream>>>(dstA[0], dstA[1], dstA[2], counts,
                                                   rank16, E, off1, off2);
    k_chunksum<<<nChunk, B, 0, stream>>>(counts, chunkSum, nTot);
    k_scanchunk<<<1, 1024, 0, stream>>>(chunkSum, chunkOff, nChunk);
    k_rowstart<<<nChunk, B, 0, stream>>>(counts, chunkOff, rowStart, nTot);
    k_fill3<<<(3 * E + B - 1) / B, B, 0, stream>>>(srcA[0], dstA[0], srcA[1], dstA[1],
                                                   srcA[2], dstA[2], as0, as1, as2,
                                                   rowStart, rank16, ePair, E, off1, off2);

    // conv0 + conv2 -> artwork block (fused agg), then conv1 -> artist block
    k_gemm_mfma<<<(Na + 63) / 64, B, 0, stream>>>(x_artist,  Wt + 0 * HD * HD, hs0, Na);
    k_gemm_mfma<<<(Nw + 63) / 64, B, 0, stream>>>(x_artwork, Wt + 2 * HD * HD, hs2, Nw);
    k_agg02<<<(Nw + 3) / 4, B, 0, stream>>>(ePair, rowStart, counts, ad0, ad2,
                                            hs0, hs2, b, b + 2 * HD,
                                            out + (size_t)Na * HD, Nw, off2);
    k_gemm_mfma<<<(Nw + 63) / 64, B, 0, stream>>>(x_artwork, Wt + 1 * HD * HD, hs2, Nw);
    int nw1 = (Na + 1) / 2;
    k_agg1<<<(nw1 + 3) / 4, B, 0, stream>>>(ePair, rowStart + off1, counts + off1,
                                            ad1, hs2, b + HD, out, Na);
}

// Round 7
// 282.736 us; speedup vs baseline: 1.8569x; 1.2888x over previous
//
#include <hip/hip_runtime.h>
#include <hip/hip_bf16.h>

#define HD 128
#define NEG_SLOPE 0.2f

typedef __attribute__((ext_vector_type(8))) short short8;
typedef __attribute__((ext_vector_type(4))) float f32x4;

__device__ __forceinline__ float lrelu(float x) {
    return x > 0.f ? x : NEG_SLOPE * x;
}
__device__ __forceinline__ ushort f2bf(float f) {
    __hip_bfloat16 h = __float2bfloat16(f);
    return *(ushort*)&h;
}
__device__ __forceinline__ float bflo(unsigned u) { return __uint_as_float(u << 16); }
__device__ __forceinline__ float bfhi(unsigned u) { return __uint_as_float(u & 0xffff0000u); }

// ---------- prep: zero counts + pack v-vectors into bf16 B-frags + Wt transpose ----
// v[c][sd] routing: (0,s)->vfA[0] (as0), (1,d)->vfA[1] (ad1),
//                   (0,d)->vfW[0] (ad0), (1,s)->vfW[1] (as1),
//                   (2,s)->vfW[2] (as2), (2,d)->vfW[3] (ad2)
__global__ void k_prep(const float* __restrict__ Ws, const float* __restrict__ Wd,
                       const float* __restrict__ a_s, const float* __restrict__ a_d,
                       ushort* __restrict__ Wt, ushort* __restrict__ vfA,
                       ushort* __restrict__ vfW, int* __restrict__ counts, int nTot) {
    int t = blockIdx.x * blockDim.x + threadIdx.x;
    if (t < nTot) counts[t] = 0;
    if (t < 768) {
        int c = t >> 8;
        int sd = (t >> 7) & 1;
        int d = t & (HD - 1);
        const float* W = sd ? Wd : Ws;
        const float* a = sd ? a_d : a_s;
        const float* Wrow = W + ((size_t)c * HD + d) * HD;
        const float* av = a + c * HD;
        float s = 0.f;
        for (int h = 0; h < HD; h++) s += Wrow[h] * av[h];
        ushort bs = f2bf(s);
        if (c == 0 && sd == 0)      vfA[0 * HD + d] = bs;
        else if (c == 1 && sd == 1) vfA[1 * HD + d] = bs;
        else if (c == 0 && sd == 1) vfW[0 * HD + d] = bs;
        else if (c == 1 && sd == 0) vfW[1 * HD + d] = bs;
        else if (c == 2 && sd == 0) vfW[2 * HD + d] = bs;
        else                        vfW[3 * HD + d] = bs;
    }
    int z = t - 768;
    if (z >= 0 && z < 14 * HD) vfA[2 * HD + z] = 0;     // zero unused vfA rows 2..15
    int z2 = t - 768 - 14 * HD;
    if (z2 >= 0 && z2 < 12 * HD) vfW[4 * HD + z2] = 0;  // zero unused vfW rows 4..15
    int u = t - 768 - 14 * HD - 12 * HD;
    if (u >= 0 && u < 3 * HD * HD) {
        int c = u >> 14;
        int r = u & 16383;
        int n = r >> 7, k = r & 127;
        Wt[u] = f2bf(Ws[((size_t)c << 14) + k * HD + n]);
    }
}

// ---------- GEMM body: H16 = bf16(X * Wt^T); NV>0 also emits alpha columns ----------
// alpha tile: one extra 16-col B-frag (vfrag) -> C[row][j] = x_row . v_j
template<int NV>
__device__ __forceinline__ void gemm_body(int blk, const float* __restrict__ X,
        const ushort* __restrict__ Wt, const ushort* __restrict__ vfrag,
        ushort* __restrict__ H16,
        float* __restrict__ a0, float* __restrict__ a1,
        float* __restrict__ a2, float* __restrict__ a3, int nrows) {
    int tid = threadIdx.x;
    int lane = tid & 63;
    int wv = tid >> 6;
    int m = lane & 15;
    int kb = lane >> 4;
    long long row0 = (long long)blk * 64 + wv * 16;
    long long ar = row0 + m;
    if (ar >= nrows) ar = nrows - 1;               // clamped read, stores guarded
    const float* aptr = X + ar * HD + kb * 8;
    const ushort* bptr = Wt + (size_t)m * HD + kb * 8;

    f32x4 acc[8];
    #pragma unroll
    for (int t = 0; t < 8; t++) acc[t] = (f32x4){0.f, 0.f, 0.f, 0.f};
    f32x4 aacc = (f32x4){0.f, 0.f, 0.f, 0.f};

    #pragma unroll
    for (int ks = 0; ks < 4; ks++) {
        float4 A0 = *(const float4*)(aptr + ks * 32);
        float4 A1 = *(const float4*)(aptr + ks * 32 + 4);
        short8 af;
        af[0] = (short)f2bf(A0.x); af[1] = (short)f2bf(A0.y);
        af[2] = (short)f2bf(A0.z); af[3] = (short)f2bf(A0.w);
        af[4] = (short)f2bf(A1.x); af[5] = (short)f2bf(A1.y);
        af[6] = (short)f2bf(A1.z); af[7] = (short)f2bf(A1.w);
        #pragma unroll
        for (int t = 0; t < 8; t++) {
            short8 bf = *(const short8*)(bptr + (size_t)t * 16 * HD + ks * 32);
            acc[t] = __builtin_amdgcn_mfma_f32_16x16x32_bf16(af, bf, acc[t], 0, 0, 0);
        }
        if (NV > 0) {
            short8 vf = *(const short8*)(vfrag + (size_t)m * HD + kb * 8 + ks * 32);
            aacc = __builtin_amdgcn_mfma_f32_16x16x32_bf16(af, vf, aacc, 0, 0, 0);
        }
    }
    int rb = kb * 4;
    #pragma unroll
    for (int t = 0; t < 8; t++) {
        #pragma unroll
        for (int j = 0; j < 4; j++) {
            long long r = row0 + rb + j;
            if (r < nrows) H16[r * HD + t * 16 + m] = f2bf(acc[t][j]);
        }
    }
    if (NV > 0 && m < NV) {
        float* ao = (m == 0) ? a0 : (m == 1) ? a1 : (m == 2) ? a2 : a3;
        #pragma unroll
        for (int j = 0; j < 4; j++) {
            long long r = row0 + rb + j;
            if (r < nrows) ao[r] = aacc[j];
        }
    }
}

// ---------- fused: CSR hist+rank (fabric-bound) co-run with gemm0a + gemm2a --------
// Bresenham spread: gemm blocks interleaved through dispatch order so both kinds
// co-reside on CUs (hist uses fabric atomics, gemm uses MFMA: disjoint pipes).
__global__ __launch_bounds__(256) void k_hist_gemm(
        const int* __restrict__ d0, const int* __restrict__ d1, const int* __restrict__ d2,
        int* __restrict__ counts, ushort* __restrict__ rank16, int E, int off1, int off2,
        const float* __restrict__ xa, int Na, const ushort* __restrict__ Wt0,
        const ushort* __restrict__ vfA, ushort* __restrict__ hs0,
        float* __restrict__ as0, float* __restrict__ ad1, int g0B,
        const float* __restrict__ xw, int Nw, const ushort* __restrict__ Wt2,
        const ushort* __restrict__ vfW, ushort* __restrict__ hs2,
        float* __restrict__ ad0, float* __restrict__ as1,
        float* __restrict__ as2, float* __restrict__ ad2,
        int ngemm, int total) {
    int b = blockIdx.x;
    int g0 = (int)(((long long)b * ngemm) / total);
    int g1 = (int)(((long long)(b + 1) * ngemm) / total);
    if (g1 > g0) {
        // gemm block #g0
        if (g0 < g0B)
            gemm_body<2>(g0, xa, Wt0, vfA, hs0, as0, ad1, nullptr, nullptr, Na);
        else
            gemm_body<4>(g0 - g0B, xw, Wt2, vfW, hs2, ad0, as1, as2, ad2, Nw);
    } else {
        int hb = b - g0;  // hist block index
        int t = hb * 256 + threadIdx.x;
        if (t >= 3 * E) return;
        int gd;
        if (t < E)           gd = d0[t];
        else if (t < 2 * E)  gd = off1 + d1[t - E];
        else                 gd = off2 + d2[t - 2 * E];
        rank16[t] = (ushort)atomicAdd(&counts[gd], 1);
    }
}

// ---------- standalone gemm (conv1, no alphas) ----------
__global__ __launch_bounds__(256) void k_gemm1(const float* __restrict__ X,
        const ushort* __restrict__ Wt, ushort* __restrict__ H16, int nrows) {
    gemm_body<0>(blockIdx.x, X, Wt, nullptr, H16, nullptr, nullptr, nullptr, nullptr, nrows);
}

__global__ void k_chunksum(const int* __restrict__ counts, int* __restrict__ chunkSum, int n) {
    __shared__ int sh[256];
    int i = blockIdx.x * 256 + threadIdx.x;
    sh[threadIdx.x] = (i < n) ? counts[i] : 0;
    __syncthreads();
    for (int off = 128; off; off >>= 1) {
        if (threadIdx.x < off) sh[threadIdx.x] += sh[threadIdx.x + off];
        __syncthreads();
    }
    if (threadIdx.x == 0) chunkSum[blockIdx.x] = sh[0];
}

__global__ void k_scanchunk(const int* __restrict__ chunkSum, int* __restrict__ chunkOff, int nChunk) {
    __shared__ int sh[1024];
    int t = threadIdx.x;
    int v = (t < nChunk) ? chunkSum[t] : 0;
    sh[t] = v;
    __syncthreads();
    for (int off = 1; off < 1024; off <<= 1) {
        int add = (t >= off) ? sh[t - off] : 0;
        __syncthreads();
        sh[t] += add;
        __syncthreads();
    }
    if (t < nChunk) chunkOff[t] = sh[t] - v; // exclusive
}

__global__ void k_rowstart(const int* __restrict__ counts, const int* __restrict__ chunkOff,
                           int* __restrict__ rowStart, int n) {
    __shared__ int sh[256];
    int i = blockIdx.x * 256 + threadIdx.x;
    int t = threadIdx.x;
    int v = (i < n) ? counts[i] : 0;
    sh[t] = v;
    __syncthreads();
    for (int off = 1; off < 256; off <<= 1) {
        int add = (t >= off) ? sh[t - off] : 0;
        __syncthreads();
        sh[t] += add;
        __syncthreads();
    }
    if (i < n) rowStart[i] = chunkOff[blockIdx.x] + sh[t] - v;
}

// ---------- atomic-free CSR fill: ePair[slot] = {src, alpha_s[src]} ----------
__global__ void k_fill3(const int* __restrict__ s0, const int* __restrict__ d0,
                        const int* __restrict__ s1, const int* __restrict__ d1,
                        const int* __restrict__ s2, const int* __restrict__ d2,
                        const float* __restrict__ as0, const float* __restrict__ as1,
                        const float* __restrict__ as2,
                        const int* __restrict__ rowStart, const ushort* __restrict__ rank16,
                        int2* __restrict__ ePair, int E, int off1, int off2) {
    int t = blockIdx.x * blockDim.x + threadIdx.x;
    if (t >= 3 * E) return;
    int sv, gd;
    const float* A;
    if (t < E)          { sv = s0[t];        gd = d0[t];        A = as0; }
    else if (t < 2 * E) { int e = t - E;     sv = s1[e]; gd = off1 + d1[e]; A = as1; }
    else                { int e = t - 2 * E; sv = s2[e]; gd = off2 + d2[e]; A = as2; }
    ePair[rowStart[gd] + rank16[t]] = make_int2(sv, __float_as_int(A[sv]));
}

// ---------- segment softmax + 4-edge-parallel gather into acc[8] ----------
__device__ __forceinline__ void seg_accum(int2 p, int dg, int base, float adv,
                                          const int2* __restrict__ ePair,
                                          const ushort* __restrict__ hs,
                                          int lane, int sub, int fl, float acc[8]) {
    if (dg <= 0) return;
    if (dg <= 64) {
        float av = (lane < dg) ? lrelu(__int_as_float(p.y) + adv) : -1e30f;
        float mm = av;
        #pragma unroll
        for (int off = 32; off; off >>= 1) mm = fmaxf(mm, __shfl_xor(mm, off, 64));
        float w = (lane < dg) ? __expf(av - mm) : 0.f;
        float den = w;
        #pragma unroll
        for (int off = 32; off; off >>= 1) den += __shfl_xor(den, off, 64);
        w *= (1.f / den);   // den >= 1 (max edge contributes exp(0))
        int s = (lane < dg) ? p.x : 0;
        for (int j0 = 0; j0 < dg; j0 += 4) {
            int idx = j0 + sub;
            float wj = __shfl(w, idx, 64);
            int sj = __shfl(s, idx, 64);
            uint4 u = *(const uint4*)((const unsigned*)hs + ((size_t)sj * HD + fl * 8) / 2);
            acc[0] += wj * bflo(u.x); acc[1] += wj * bfhi(u.x);
            acc[2] += wj * bflo(u.y); acc[3] += wj * bfhi(u.y);
            acc[4] += wj * bflo(u.z); acc[5] += wj * bfhi(u.z);
            acc[6] += wj * bflo(u.w); acc[7] += wj * bfhi(u.w);
        }
    } else {
        float mm = -1e30f;
        for (int i = lane; i < dg; i += 64) {
            int2 q = ePair[base + i];
            mm = fmaxf(mm, lrelu(__int_as_float(q.y) + adv));
        }
        #pragma unroll
        for (int off = 32; off; off >>= 1) mm = fmaxf(mm, __shfl_xor(mm, off, 64));
        float den = 0.f;
        for (int i = lane; i < dg; i += 64) {
            int2 q = ePair[base + i];
            den += __expf(lrelu(__int_as_float(q.y) + adv) - mm);
        }
        #pragma unroll
        for (int off = 32; off; off >>= 1) den += __shfl_xor(den, off, 64);
        float inv = 1.f / den;
        for (int c0 = 0; c0 < dg; c0 += 64) {
            int n = min(64, dg - c0);
            int s = 0; float w = 0.f;
            if (lane < n) {
                int2 q = ePair[base + c0 + lane];
                s = q.x;
                w = __expf(lrelu(__int_as_float(q.y) + adv) - mm) * inv;
            }
            for (int j0 = 0; j0 < n; j0 += 4) {
                int idx = j0 + sub;
                float wj = __shfl(w, idx, 64);
                int sj = __shfl(s, idx, 64);
                uint4 u = *(const uint4*)((const unsigned*)hs + ((size_t)sj * HD + fl * 8) / 2);
                acc[0] += wj * bflo(u.x); acc[1] += wj * bfhi(u.x);
                acc[2] += wj * bflo(u.y); acc[3] += wj * bfhi(u.y);
                acc[4] += wj * bflo(u.z); acc[5] += wj * bfhi(u.z);
                acc[6] += wj * bflo(u.w); acc[7] += wj * bfhi(u.w);
            }
        }
    }
}

// ---------- fused conv0+conv2 aggregate into artwork block: relu(b0+b2+accA+accB) ----
__global__ __launch_bounds__(256) void k_agg02(const int2* __restrict__ ePair,
        const int* __restrict__ rowStart, const int* __restrict__ counts,
        const float* __restrict__ ad0_, const float* __restrict__ ad2_,
        const ushort* __restrict__ hs0, const ushort* __restrict__ hs2,
        const float* __restrict__ b0, const float* __restrict__ b2,
        float* __restrict__ out, int Nw, int offR2) {
    int lane = threadIdx.x & 63;
    int d = (int)(((long long)blockIdx.x * blockDim.x + threadIdx.x) >> 6);
    if (d >= Nw) return;
    int sub = lane >> 4, fl = lane & 15;

    int dgA = counts[d],         bA = rowStart[d];
    int dgB = counts[offR2 + d], bB = rowStart[offR2 + d];
    float aA = ad0_[d], aB = ad2_[d];
    int2 pA = make_int2(0, 0), pB = make_int2(0, 0);
    if (dgA > 0 && dgA <= 64 && lane < dgA) pA = ePair[bA + lane];
    if (dgB > 0 && dgB <= 64 && lane < dgB) pB = ePair[bB + lane];

    float acc[8];
    #pragma unroll
    for (int k = 0; k < 8; k++) acc[k] = 0.f;
    seg_accum(pA, dgA, bA, aA, ePair, hs0, lane, sub, fl, acc);
    seg_accum(pB, dgB, bB, aB, ePair, hs2, lane, sub, fl, acc);

    #pragma unroll
    for (int k = 0; k < 8; k++) {
        acc[k] += __shfl_xor(acc[k], 16, 64);
        acc[k] += __shfl_xor(acc[k], 32, 64);
    }
    if (lane < 16) {
        float* orow = out + (size_t)d * HD + fl * 8;
        float vals[8];
        #pragma unroll
        for (int k = 0; k < 8; k++)
            vals[k] = fmaxf(b0[fl * 8 + k] + b2[fl * 8 + k] + acc[k], 0.f);
        *(float4*)&orow[0] = make_float4(vals[0], vals[1], vals[2], vals[3]);
        *(float4*)&orow[4] = make_float4(vals[4], vals[5], vals[6], vals[7]);
    }
}

// ---------- conv1 aggregate into artist block, 2 dsts per wave: relu(b1+acc) --------
__global__ __launch_bounds__(256) void k_agg1(const int2* __restrict__ ePair,
        const int* __restrict__ rowStart, const int* __restrict__ counts,
        const float* __restrict__ ad_, const ushort* __restrict__ hs,
        const float* __restrict__ bias, float* __restrict__ out, int Nd) {
    int lane = threadIdx.x & 63;
    int w = (int)(((long long)blockIdx.x * blockDim.x + threadIdx.x) >> 6);
    int d0 = 2 * w, d1 = 2 * w + 1;
    if (d0 >= Nd) return;
    int sub = lane >> 4, fl = lane & 15;

    int dg0 = counts[d0], b0 = rowStart[d0];
    float a0 = ad_[d0];
    int dg1 = 0, b1 = 0; float a1 = 0.f;
    if (d1 < Nd) { dg1 = counts[d1]; b1 = rowStart[d1]; a1 = ad_[d1]; }
    int2 p0 = make_int2(0, 0), p1 = make_int2(0, 0);
    if (dg0 > 0 && dg0 <= 64 && lane < dg0) p0 = ePair[b0 + lane];
    if (dg1 > 0 && dg1 <= 64 && lane < dg1) p1 = ePair[b1 + lane];

    float acc0[8], acc1[8];
    #pragma unroll
    for (int k = 0; k < 8; k++) { acc0[k] = 0.f; acc1[k] = 0.f; }
    seg_accum(p0, dg0, b0, a0, ePair, hs, lane, sub, fl, acc0);
    seg_accum(p1, dg1, b1, a1, ePair, hs, lane, sub, fl, acc1);

    #pragma unroll
    for (int k = 0; k < 8; k++) {
        acc0[k] += __shfl_xor(acc0[k], 16, 64);
        acc0[k] += __shfl_xor(acc0[k], 32, 64);
        acc1[k] += __shfl_xor(acc1[k], 16, 64);
        acc1[k] += __shfl_xor(acc1[k], 32, 64);
    }
    if (lane < 16) {
        float* orow = out + (size_t)d0 * HD + fl * 8;
        float vals[8];
        #pragma unroll
        for (int k = 0; k < 8; k++)
            vals[k] = fmaxf(bias[fl * 8 + k] + acc0[k], 0.f);
        *(float4*)&orow[0] = make_float4(vals[0], vals[1], vals[2], vals[3]);
        *(float4*)&orow[4] = make_float4(vals[4], vals[5], vals[6], vals[7]);
        if (d1 < Nd) {
            float* orow1 = out + (size_t)d1 * HD + fl * 8;
            #pragma unroll
            for (int k = 0; k < 8; k++)
                vals[k] = fmaxf(bias[fl * 8 + k] + acc1[k], 0.f);
            *(float4*)&orow1[0] = make_float4(vals[0], vals[1], vals[2], vals[3]);
            *(float4*)&orow1[4] = make_float4(vals[4], vals[5], vals[6], vals[7]);
        }
    }
}

extern "C" void kernel_launch(void* const* d_in, const int* in_sizes, int n_in,
                              void* d_out, int out_size, void* d_ws, size_t ws_size,
                              hipStream_t stream) {
    const float* x_artist  = (const float*)d_in[0];
    const float* x_artwork = (const float*)d_in[1];
    const int* srcA[3] = {(const int*)d_in[2], (const int*)d_in[4], (const int*)d_in[6]};
    const int* dstA[3] = {(const int*)d_in[3], (const int*)d_in[5], (const int*)d_in[7]};
    const float* Ws  = (const float*)d_in[8];
    const float* Wd  = (const float*)d_in[9];
    const float* a_s = (const float*)d_in[10];
    const float* a_d = (const float*)d_in[11];
    const float* b   = (const float*)d_in[12];
    float* out = (float*)d_out;

    const int Na = in_sizes[0] / HD;
    const int Nw = in_sizes[1] / HD;
    const int E  = in_sizes[2];
    const int nTot = Nw + Na + Nw;              // concatenated dst-node space
    const int nChunk = (nTot + 255) / 256;      // <= 1024 required

    // ---- workspace carve-up (4-byte words; every chunk starts 16B-aligned) ----
    float* ws = (float*)d_ws;
    size_t off = 0;
    float* as0 = ws + off;  off += Na;
    float* ad1 = ws + off;  off += Na;
    float* ad0 = ws + off;  off += Nw;
    float* as1 = ws + off;  off += Nw;
    float* as2 = ws + off;  off += Nw;
    float* ad2 = ws + off;  off += Nw;
    int* counts   = (int*)(ws + off); off += nTot;
    int* chunkSum = (int*)(ws + off); off += 1024;
    int* chunkOff = (int*)(ws + off); off += 1024;
    int* rowStart = (int*)(ws + off); off += nTot;
    int2* ePair   = (int2*)(ws + off); off += (size_t)2 * 3 * E;
    ushort* rank16 = (ushort*)(ws + off); off += ((size_t)3 * E + 1) / 2;
    ushort* Wt    = (ushort*)(ws + off); off += (3 * HD * HD) / 2;
    ushort* vfA   = (ushort*)(ws + off); off += (16 * HD) / 2;
    ushort* vfW   = (ushort*)(ws + off); off += (16 * HD) / 2;
    ushort* hs0   = (ushort*)(ws + off); off += (size_t)Na * HD / 2;   // artist hs (conv0)
    ushort* hs2   = (ushort*)(ws + off); off += (size_t)Nw * HD / 2;   // artwork hs (conv2, then conv1)
    if (ws_size < off * sizeof(float) || nChunk > 1024) return;

    const int off1 = Nw, off2 = Nw + Na;
    const int B = 256;

    k_prep<<<(nTot + B - 1) / B, B, 0, stream>>>(Ws, Wd, a_s, a_d, Wt, vfA, vfW, counts, nTot);

    // fused: CSR hist (fabric-atomic-bound) co-runs with gemm0a + gemm2a (MFMA-bound)
    const int histB = (3 * E + B - 1) / B;
    const int g0B = (Na + 63) / 64;
    const int g2B = (Nw + 63) / 64;
    const int ngemm = g0B + g2B;
    const int total = histB + ngemm;
    k_hist_gemm<<<total, B, 0, stream>>>(dstA[0], dstA[1], dstA[2], counts, rank16,
                                         E, off1, off2,
                                         x_artist, Na, Wt + 0 * HD * HD, vfA, hs0,
                                         as0, ad1, g0B,
                                         x_artwork, Nw, Wt + 2 * HD * HD, vfW, hs2,
                                         ad0, as1, as2, ad2,
                                         ngemm, total);

    // scan -> rowStart
    k_chunksum<<<nChunk, B, 0, stream>>>(counts, chunkSum, nTot);
    k_scanchunk<<<1, 1024, 0, stream>>>(chunkSum, chunkOff, nChunk);
    k_rowstart<<<nChunk, B, 0, stream>>>(counts, chunkOff, rowStart, nTot);

    // atomic-free fill with {src, alpha_s} pairs
    k_fill3<<<(3 * E + B - 1) / B, B, 0, stream>>>(srcA[0], dstA[0], srcA[1], dstA[1],
                                                   srcA[2], dstA[2], as0, as1, as2,
                                                   rowStart, rank16, ePair, E, off1, off2);

    // conv0+conv2 -> artwork block, then conv1 gemm + agg -> artist block
    k_agg02<<<(Nw + 3) / 4, B, 0, stream>>>(ePair, rowStart, counts, ad0, ad2,
                                            hs0, hs2, b, b + 2 * HD,
                                            out + (size_t)Na * HD, Nw, off2);
    k_gemm1<<<(Nw + 63) / 64, B, 0, stream>>>(x_artwork, Wt + 1 * HD * HD, hs2, Nw);
    int nw1 = (Na + 1) / 2;
    k_agg1<<<(nw1 + 3) / 4, B, 0, stream>>>(ePair, rowStart + off1, counts + off1,
                                            ad1, hs2, b + HD, out, Na);
}